// Round 2
// 181.776 us; speedup vs baseline: 1.0204x; 1.0204x over previous
//
#include <hip/hip_runtime.h>
#include <math.h>

#define N_NODES 16384
#define D_MODEL 256
#define H_HEADS 4
#define C_CH 256
#define E_EDGES 65536
#define ETOT (E_EDGES + N_NODES)
#define HC 1024

typedef __bf16 bf16x8 __attribute__((ext_vector_type(8)));
typedef __bf16 bf16x4 __attribute__((ext_vector_type(4)));
typedef float f32x4 __attribute__((ext_vector_type(4)));

__device__ __forceinline__ __bf16 f2bf(float f) { return (__bf16)f; }
__device__ __forceinline__ float bf2f(__bf16 b) { return (float)b; }

// ==== prep1_ln: 0..63 t-partials | 64..319 compose_v | 320..639 hist |
//                640..4735 LayerNorm (independent of prep outputs) ====
__global__ __launch_bounds__(256) void prep1_ln(
    const float* __restrict__ Wg, const float* __restrict__ att_src,
    const float* __restrict__ att_dst, const float* __restrict__ W2,
    const int* __restrict__ ei, const float* __restrict__ in,
    const float* __restrict__ gamma, const float* __restrict__ beta,
    float* __restrict__ t, float* __restrict__ V, int* __restrict__ deg,
    __bf16* __restrict__ x_ln)
{
    int b = blockIdx.x;
    int tid = threadIdx.x;
    if (b >= 640) {
        int wave = tid >> 6, lane = tid & 63;
        int row = (b - 640) * 4 + wave;
        float4 v = ((const float4*)(in + (size_t)row * D_MODEL))[lane];
        float s  = v.x + v.y + v.z + v.w;
        float sq = v.x*v.x + v.y*v.y + v.z*v.z + v.w*v.w;
        for (int off = 32; off; off >>= 1) {
            s  += __shfl_xor(s,  off);
            sq += __shfl_xor(sq, off);
        }
        float mean = s * (1.0f / D_MODEL);
        float var  = sq * (1.0f / D_MODEL) - mean * mean;
        float inv  = rsqrtf(var + 1e-6f);
        float4 g = ((const float4*)gamma)[lane];
        float4 bb = ((const float4*)beta)[lane];
        bf16x4 o;
        o[0] = f2bf((v.x - mean) * inv * g.x + bb.x);
        o[1] = f2bf((v.y - mean) * inv * g.y + bb.y);
        o[2] = f2bf((v.z - mean) * inv * g.z + bb.z);
        o[3] = f2bf((v.w - mean) * inv * g.w + bb.w);
        *(bf16x4*)(x_ln + (size_t)row * D_MODEL + lane * 4) = o;
        return;
    }
    if (b < 64) {
        int v = b >> 3, sl = b & 7, h = v & 3;
        const float* att = ((v < 4) ? att_src : att_dst) + h * C_CH;
        float acc = 0.f;
        #pragma unroll
        for (int j = 0; j < 32; ++j) {
            int c = sl * 32 + j;
            acc = fmaf(Wg[(size_t)(h * 256 + c) * 256 + tid], att[c], acc);
        }
        atomicAdd(&t[v * 256 + tid], acc);
    } else if (b < 320) {
        int bb = b - 64;
        int og = (bb & 63) * 4, h = bb >> 6;
        const float* w2r = W2 + (size_t)og * 256;
        const float* wgp = Wg + ((size_t)h * 256) * 256 + tid;
        float a0 = 0.f, a1 = 0.f, a2 = 0.f, a3 = 0.f;
        #pragma unroll 4
        for (int c = 0; c < 256; ++c) {
            float wv = wgp[(size_t)c * 256];
            a0 = fmaf(w2r[c],       wv, a0);
            a1 = fmaf(w2r[256 + c], wv, a1);
            a2 = fmaf(w2r[512 + c], wv, a2);
            a3 = fmaf(w2r[768 + c], wv, a3);
        }
        size_t base = (size_t)og * 1024 + h * 256 + tid;
        V[base]        = a0;
        V[base + 1024] = a1;
        V[base + 2048] = a2;
        V[base + 3072] = a3;
    } else {
        int e = (b - 320) * 256 + tid;
        int dst = (e < E_EDGES) ? ei[E_EDGES + e] : (e - E_EDGES);
        atomicAdd(deg + dst, 1);
    }
}

// ==== prep2: blocks 0..63 u2/c0 | 64..319 compose_wz + bias_z | 320 scan ====
__global__ __launch_bounds__(256) void prep2(
    const float* __restrict__ t, const float* __restrict__ W1,
    const float* __restrict__ b1, const float* __restrict__ V,
    const float* __restrict__ W2, const float* __restrict__ bg,
    const float* __restrict__ b2, float* __restrict__ u2,
    float* __restrict__ c0, __bf16* __restrict__ Wz,
    float* __restrict__ bias_z, const int* __restrict__ deg,
    int* __restrict__ row_st)
{
    int b = blockIdx.x;
    int d = threadIdx.x;
    if (b < 64) {
        int v = b >> 3, sl = b & 7;
        const float* tv = t + v * 256;
        float acc = 0.f;
        #pragma unroll
        for (int j = 0; j < 32; ++j) {
            int k = sl * 32 + j;
            acc = fmaf(tv[k], W1[(size_t)k * 256 + d], acc);
        }
        atomicAdd(&u2[v * 256 + d], acc);
        if (d < 32) {
            float p = tv[sl * 32 + d] * b1[sl * 32 + d];
            for (int s = 16; s; s >>= 1) p += __shfl_xor(p, s);
            if (d == 0) atomicAdd(&c0[v], p);
        }
        return;
    }
    if (b == 320) {
        __shared__ int wsum[4];
        int lane = d & 63, wid = d >> 6;
        int base = d * 64;
        int run = 0;
        for (int j = 0; j < 64; ++j) run += deg[base + j];
        int x = run;
        #pragma unroll
        for (int off = 1; off < 64; off <<= 1) {
            int y = __shfl_up(x, off);
            if (lane >= off) x += y;
        }
        if (lane == 63) wsum[wid] = x;
        __syncthreads();
        int woff = 0;
        #pragma unroll
        for (int wdx = 0; wdx < 4; ++wdx)
            if (wdx < wid) woff += wsum[wdx];
        int excl = woff + x - run;
        int run2 = 0;
        for (int j = 0; j < 64; ++j) {
            row_st[base + j] = excl + run2;
            run2 += deg[base + j];
        }
        if (d == 255) row_st[N_NODES] = excl + run2;
        return;
    }
    int bb = b - 64;
    int og = (bb & 63) * 4, h = bb >> 6;
    int lane = d & 63, wid = d >> 6;
    const float* vr = V + (size_t)og * 1024 + h * 256;
    float a0 = 0.f, a1 = 0.f, a2 = 0.f, a3 = 0.f;
    #pragma unroll 4
    for (int k = 0; k < 256; ++k) {
        float w1v = W1[(size_t)k * 256 + d];
        a0 = fmaf(vr[k],        w1v, a0);
        a1 = fmaf(vr[1024 + k], w1v, a1);
        a2 = fmaf(vr[2048 + k], w1v, a2);
        a3 = fmaf(vr[3072 + k], w1v, a3);
    }
    size_t base = (size_t)og * 1024 + h * 256 + d;
    Wz[base]        = f2bf(a0);
    Wz[base + 1024] = f2bf(a1);
    Wz[base + 2048] = f2bf(a2);
    Wz[base + 3072] = f2bf(a3);

    __shared__ float red[4][4];
    float b1v = b1[d];
    #pragma unroll
    for (int j = 0; j < 4; ++j) {
        float p = vr[(size_t)j * 1024 + d] * b1v;
        for (int s = 32; s; s >>= 1) p += __shfl_xor(p, s);
        if (lane == 0) red[j][wid] = p;
    }
    __syncthreads();
    if (d < 4) {
        float s = red[d][0] + red[d][1] + red[d][2] + red[d][3];
        atomicAdd(&bias_z[og + d], 0.25f * s);
    }
    if (h == 0) {
        __syncthreads();
        float bgv = bg[d];
        #pragma unroll
        for (int j = 0; j < 4; ++j) {
            float q = W2[(size_t)(og + j) * 256 + d] * bgv;
            for (int s = 32; s; s >>= 1) q += __shfl_xor(q, s);
            if (lane == 0) red[j][wid] = q;
        }
        __syncthreads();
        if (d < 4) {
            float s = red[d][0] + red[d][1] + red[d][2] + red[d][3];
            atomicAdd(&bias_z[og + d], s + b2[og + d]);
        }
    }
}

// ==== logits_scatter: blocks 0..4095 logits (wave/node) | 4096..4415 scatter ====
__global__ __launch_bounds__(256) void logits_scatter(
    const __bf16* __restrict__ x_ln, const float* __restrict__ u2,
    const float* __restrict__ c0, float* __restrict__ a_src,
    float* __restrict__ a_dst, const int* __restrict__ ei,
    const int* __restrict__ row_st, int* __restrict__ cnt,
    int* __restrict__ csr_src)
{
    int b = blockIdx.x;
    int tid = threadIdx.x;
    if (b >= 4096) {
        int e = (b - 4096) * 256 + tid;
        int src, dst;
        if (e < E_EDGES) { src = ei[e]; dst = ei[E_EDGES + e]; }
        else             { src = dst = e - E_EDGES; }
        int pos = atomicAdd(cnt + dst, 1);
        csr_src[row_st[dst] + pos] = src;
        return;
    }
    __shared__ float u2s[8][256];
    __shared__ float c0s[8];
    #pragma unroll
    for (int k = 0; k < 8; ++k) u2s[k][tid] = u2[k * 256 + tid];
    if (tid < 8) c0s[tid] = c0[tid];
    __syncthreads();

    int wave = tid >> 6, lane = tid & 63;
    int n = b * 4 + wave;
    int v = lane >> 3, p = lane & 7;
    const __bf16* xp = x_ln + (size_t)n * D_MODEL + p * 32;
    const float*  up = &u2s[v][p * 32];
    float acc = 0.f;
    #pragma unroll
    for (int ti = 0; ti < 4; ++ti) {
        bf16x8 x = *(const bf16x8*)(xp + ti * 8);
        #pragma unroll
        for (int j = 0; j < 8; ++j)
            acc = fmaf(bf2f(x[j]), up[ti * 8 + j], acc);
    }
    acc += __shfl_xor(acc, 1);
    acc += __shfl_xor(acc, 2);
    acc += __shfl_xor(acc, 4);
    if (p == 0) {
        float o = acc + c0s[v];
        if (v < 4) a_src[n * H_HEADS + v] = o;
        else       a_dst[n * H_HEADS + (v - 4)] = o;
    }
}

// ---- fused softmax + aggregation, single pass (shift-invariant softmax) ----
__global__ __launch_bounds__(256) void gat_fused(
    const __bf16* __restrict__ x_ln, const float* __restrict__ a_src,
    const float* __restrict__ a_dst, const int* __restrict__ row_start,
    const int* __restrict__ csr_src, __bf16* __restrict__ agg)
{
    int wave = threadIdx.x >> 6, lane = threadIdx.x & 63;
    int i = blockIdx.x * 4 + wave;
    int rs = row_start[i], deg = row_start[i + 1] - rs;
    float4 ad = *(const float4*)(a_dst + i * H_HEADS);

    float acc[4][4] = {};
    float sm0 = 0.f, sm1 = 0.f, sm2 = 0.f, sm3 = 0.f;
    for (int e = 0; e < deg; ++e) {
        int s = csr_src[rs + e];
        float4 as = *(const float4*)(a_src + s * H_HEADS);
        float l0 = as.x + ad.x, l1 = as.y + ad.y, l2 = as.z + ad.z, l3 = as.w + ad.w;
        l0 = (l0 > 0.f) ? l0 : 0.2f * l0;
        l1 = (l1 > 0.f) ? l1 : 0.2f * l1;
        l2 = (l2 > 0.f) ? l2 : 0.2f * l2;
        l3 = (l3 > 0.f) ? l3 : 0.2f * l3;
        float w0 = __expf(l0), w1 = __expf(l1);
        float w2 = __expf(l2), w3 = __expf(l3);
        sm0 += w0; sm1 += w1; sm2 += w2; sm3 += w3;
        bf16x4 x = *(const bf16x4*)(x_ln + (size_t)s * D_MODEL + lane * 4);
        #pragma unroll
        for (int j = 0; j < 4; ++j) {
            float xv = bf2f(x[j]);
            acc[0][j] = fmaf(w0, xv, acc[0][j]);
            acc[1][j] = fmaf(w1, xv, acc[1][j]);
            acc[2][j] = fmaf(w2, xv, acc[2][j]);
            acc[3][j] = fmaf(w3, xv, acc[3][j]);
        }
    }
    float sc[4] = {0.25f / sm0, 0.25f / sm1, 0.25f / sm2, 0.25f / sm3};
    #pragma unroll
    for (int h = 0; h < 4; ++h) {
        bf16x4 o;
        #pragma unroll
        for (int j = 0; j < 4; ++j) o[j] = f2bf(acc[h][j] * sc[h]);
        *(bf16x4*)(agg + (size_t)i * HC + h * 256 + lane * 4) = o;
    }
}

// -------- skinny bf16 GEMM: out[M,256] = A[M,K]·B[256,K]^T + bias + resid --------
// One block per 64-row A-panel, full N=256 width: A is fetched from HBM exactly
// once (the old dim3(4,256) grid put the 4 blocks sharing an A-panel on 4
// different XCDs -> 4x A over-fetch = 128 MB). Grid = 256 blocks = 1/CU.
// 4 waves, each owns a 64x64 quadrant (4x4 frags of 16x16x32).
// BK=64, reg double-buffer: loads for stage k+1 issue before LDS-write/compute
// of stage k so HBM latency hides under MFMA (no other block on the CU to hide it).
// LDS row stride 72 bf16 = 144 B (16B-aligned, stride%32dw == 4 -> conflict-free class).
#define APAD 72

__global__ __launch_bounds__(256) void gemm_skinny(
    const __bf16* __restrict__ A, const __bf16* __restrict__ B,
    const float* __restrict__ bias, const float* __restrict__ resid,
    float* __restrict__ outf, int K)
{
    __shared__ __align__(16) __bf16 As[64 * APAD];
    __shared__ __align__(16) __bf16 Bs[256 * APAD];
    int tid  = threadIdx.x;
    int lane = tid & 63;
    int w    = tid >> 6;
    int quad = lane >> 4;
    int l16  = lane & 15;
    int m0 = blockIdx.x * 64;
    int n0 = w * 64;

    int srow = tid >> 3, sp = tid & 7;
    const __bf16* Ab = A + (size_t)(m0 + srow) * K + sp * 8;
    const __bf16* Bb = B + (size_t)srow * K + sp * 8;
    size_t rstride = (size_t)32 * K;

    f32x4 acc[4][4] = {};

    bf16x8 a0_0, a0_1, b0_[8];
    bf16x8 a1_0, a1_1, b1_[8];

    auto compute = [&]() {
        #pragma unroll
        for (int ks = 0; ks < 2; ++ks) {
            bf16x8 af[4], bfr[4];
            #pragma unroll
            for (int mt = 0; mt < 4; ++mt)
                af[mt] = *(const bf16x8*)(As + (mt * 16 + l16) * APAD
                                          + ks * 32 + quad * 8);
            #pragma unroll
            for (int nt = 0; nt < 4; ++nt)
                bfr[nt] = *(const bf16x8*)(Bs + (n0 + nt * 16 + l16) * APAD
                                           + ks * 32 + quad * 8);
            #pragma unroll
            for (int mt = 0; mt < 4; ++mt)
                #pragma unroll
                for (int nt = 0; nt < 4; ++nt)
                    acc[mt][nt] = __builtin_amdgcn_mfma_f32_16x16x32_bf16(
                        af[mt], bfr[nt], acc[mt][nt], 0, 0, 0);
        }
    };

    // prologue: load kb=0 into buf0
    a0_0 = *(const bf16x8*)(Ab);
    a0_1 = *(const bf16x8*)(Ab + rstride);
    #pragma unroll
    for (int t = 0; t < 8; ++t)
        b0_[t] = *(const bf16x8*)(Bb + t * rstride);

    for (int kb = 0; kb < K; kb += 128) {
        // ---- stage A: consume buf0 (=kb), prefetch buf1 (=kb+64) ----
        {
            const __bf16* Ap = Ab + kb + 64;
            const __bf16* Bp = Bb + kb + 64;
            a1_0 = *(const bf16x8*)(Ap);
            a1_1 = *(const bf16x8*)(Ap + rstride);
            #pragma unroll
            for (int t = 0; t < 8; ++t)
                b1_[t] = *(const bf16x8*)(Bp + t * rstride);
        }
        __syncthreads();                       // prior stage's LDS reads done
        *(bf16x8*)(As + srow * APAD + sp * 8)        = a0_0;
        *(bf16x8*)(As + (srow + 32) * APAD + sp * 8) = a0_1;
        #pragma unroll
        for (int t = 0; t < 8; ++t)
            *(bf16x8*)(Bs + (srow + t * 32) * APAD + sp * 8) = b0_[t];
        __syncthreads();
        compute();

        // ---- stage B: consume buf1 (=kb+64), prefetch buf0 (=kb+128) ----
        if (kb + 128 < K) {
            const __bf16* Ap = Ab + kb + 128;
            const __bf16* Bp = Bb + kb + 128;
            a0_0 = *(const bf16x8*)(Ap);
            a0_1 = *(const bf16x8*)(Ap + rstride);
            #pragma unroll
            for (int t = 0; t < 8; ++t)
                b0_[t] = *(const bf16x8*)(Bp + t * rstride);
        }
        __syncthreads();
        *(bf16x8*)(As + srow * APAD + sp * 8)        = a1_0;
        *(bf16x8*)(As + (srow + 32) * APAD + sp * 8) = a1_1;
        #pragma unroll
        for (int t = 0; t < 8; ++t)
            *(bf16x8*)(Bs + (srow + t * 32) * APAD + sp * 8) = b1_[t];
        __syncthreads();
        compute();
    }

    #pragma unroll
    for (int nt = 0; nt < 4; ++nt) {
        int col = n0 + nt * 16 + l16;
        float bv = bias[col];
        #pragma unroll
        for (int mt = 0; mt < 4; ++mt) {
            int row = m0 + mt * 16 + quad * 4;
            #pragma unroll
            for (int r = 0; r < 4; ++r) {
                size_t off = (size_t)(row + r) * C_CH + col;
                outf[off] = acc[mt][nt][r] + bv + resid[off];
            }
        }
    }
}

extern "C" void kernel_launch(void* const* d_in, const int* in_sizes, int n_in,
                              void* d_out, int out_size, void* d_ws, size_t ws_size,
                              hipStream_t stream)
{
    const float* inp      = (const float*)d_in[0];
    const int*   ei       = (const int*)  d_in[1];
    const float* ln_gamma = (const float*)d_in[2];
    const float* ln_beta  = (const float*)d_in[3];
    const float* W1       = (const float*)d_in[4];
    const float* b1       = (const float*)d_in[5];
    const float* W_gat    = (const float*)d_in[6];
    const float* att_src  = (const float*)d_in[7];
    const float* att_dst  = (const float*)d_in[8];
    const float* bias_gat = (const float*)d_in[9];
    const float* W2       = (const float*)d_in[10];
    const float* b2       = (const float*)d_in[11];

    char* ws = (char*)d_ws;
    __bf16* x_ln_bf   = (__bf16*)(ws);                        //  8 MB
    __bf16* agg_bf    = (__bf16*)(ws + (8ull  << 20));        // 32 MB
    float*  V_f       = (float*)(ws + (40ull << 20));         //  1 MB
    __bf16* Wz_b      = (__bf16*)(ws + (41ull << 20));        // 512 KB
    float*  a_src_b   = (float*)(ws + (42ull << 20));         // 256 KB
    float*  a_dst_b   = a_src_b + (size_t)N_NODES * H_HEADS;  // 256 KB
    // ---- zero region start ----
    float*  t_vec     = a_dst_b + (size_t)N_NODES * H_HEADS;  //  8 KB
    float*  u2        = t_vec + 8 * 256;                      //  8 KB
    float*  c0        = u2 + 8 * 256;                         //  32 B
    float*  bias_z    = c0 + 8;                               //  1 KB
    int*    deg       = (int*)(bias_z + 256);                 // 64 KB
    int*    cnt       = deg + N_NODES;                        // 64 KB
    // ---- zero region end ----
    int*    row_st    = cnt + N_NODES;
    int*    csr_src   = row_st + N_NODES + 4;

    size_t zbytes = (8 * 256 + 8 * 256 + 8 + 256) * sizeof(float)
                  + 2 * N_NODES * sizeof(int);
    hipMemsetAsync(t_vec, 0, zbytes, stream);

    // prep1 + LayerNorm overlapped; prep2 + scan; logits + scatter
    prep1_ln<<<640 + 4096, 256, 0, stream>>>(W_gat, att_src, att_dst, W2, ei,
                                             inp, ln_gamma, ln_beta,
                                             t_vec, V_f, deg, x_ln_bf);
    prep2<<<321, 256, 0, stream>>>(t_vec, W1, b1, V_f, W2, bias_gat, b2,
                                   u2, c0, Wz_b, bias_z, deg, row_st);
    logits_scatter<<<4096 + 320, 256, 0, stream>>>(x_ln_bf, u2, c0,
                                                   a_src_b, a_dst_b,
                                                   ei, row_st, cnt, csr_src);
    gat_fused<<<N_NODES / 4, 256, 0, stream>>>(x_ln_bf, a_src_b, a_dst_b,
                                               row_st, csr_src, agg_bf);
    gemm_skinny<<<N_NODES / 64, 256, 0, stream>>>(agg_bf, Wz_b, bias_z, inp,
                                                  (float*)d_out, HC);
}